// Round 9
// baseline (142.641 us; speedup 1.0000x reference)
//
#include <hip/hip_runtime.h>

#define NPTS  65536
#define KNB   32
#define KPn   15
#define CIN   64
#define COUT  128
#define MPTS  32            // points per block (2 MFMA M-tiles)
#define THREADS 1024        // 16 waves/block; 2 blocks/CU = 32 waves/CU (max)
#define WSTRIDE 968         // wl row stride in bf16 elems (960 + 8 pad)
#define NTILE 8             // 128 cols / 16
#define KSTEPS 30           // 960 / 32
#define WELEMS (NTILE * KSTEPS * 64 * 8)    // 122880 bf16 elements

typedef __attribute__((ext_vector_type(8))) short short8;
typedef __attribute__((ext_vector_type(4))) float f32x4;

__device__ __forceinline__ unsigned int f2bf(float f) {
    union { float f; unsigned int i; } v; v.f = f;
    return (v.i + 0x7fffu + ((v.i >> 16) & 1u)) >> 16;   // RNE
}

// ---- prep: pack weights into MFMA B-fragment order (permuted K) + kpq/R2 ----
// K-enum: f = cg*120 + k*8 + j  (cg = c>>3, j = c&7)  ->  orig = k*64 + c
__global__ void wtrans_kernel(const float* __restrict__ w,
                              const float* __restrict__ kpts,
                              unsigned short* __restrict__ wTf,
                              float4* __restrict__ kpq_out) {  // [16]: 15 kpq + {R2}
    const int d = blockIdx.x * 256 + threadIdx.x;
    if (d < WELEMS) {
        const int j    = d & 7;
        const int lane = (d >> 3) & 63;
        const int ks   = (d >> 9) % KSTEPS;
        const int t    = d / (KSTEPS * 512);
        const int f    = ks * 32 + (lane >> 4) * 8 + j;
        const int cg   = f / 120;
        const int rem  = f - cg * 120;
        const int orig = (rem >> 3) * 64 + cg * 8 + (rem & 7);
        const int n    = t * 16 + (lane & 15);
        wTf[d] = (unsigned short)f2bf(w[(size_t)orig * COUT + n]);
    }
    if (blockIdx.x == 0 && threadIdx.x < 16) {
        const int k = threadIdx.x;
        if (k < KPn) {
            const float x = kpts[k * 3 + 0];
            const float y = kpts[k * 3 + 1];
            const float z = kpts[k * 3 + 2];
            kpq_out[k] = make_float4(x, y, z, x * x + y * y + z * z);
        } else {
            float mx = 0.f;
            for (int i = 0; i < KPn; ++i) {
                const float x = kpts[i * 3 + 0];
                const float y = kpts[i * 3 + 1];
                const float z = kpts[i * 3 + 2];
                mx = fmaxf(mx, x * x + y * y + z * z);
            }
            const float R = 0.1f + sqrtf(mx);
            kpq_out[15] = make_float4(R * R, 0.f, 0.f, 0.f);
        }
    }
}

// accumulate one point-half for static k: walk survivor bits, coalesced feats
#define ACC_HALF(MHALF, BASE, ACCV)                                           \
    {                                                                         \
        unsigned long long mh_ = (MHALF);                                     \
        while (mh_) {                                                         \
            const int j_ = (int)__builtin_ctzll(mh_) + (BASE);                \
            mh_ &= mh_ - 1;                                                   \
            const int nb_ = __builtin_amdgcn_readlane(nbv, j_);               \
            const unsigned int wp_ =                                          \
                (unsigned int)__builtin_amdgcn_readlane((int)wpk[k >> 1], j_);\
            const float w_ = (float)((wp_ >> (16 * (k & 1))) & 0xFFFFu) *     \
                             (1.0f / 65535.0f);                               \
            ACCV += w_ * feats[(size_t)nb_ * CIN + lane];                     \
        }                                                                     \
    }

__global__ __launch_bounds__(THREADS, 8) void kpconv_kernel(
    const float* __restrict__ pos,         // [N,3] f32
    const float* __restrict__ feats,       // [N,64] f32
    const unsigned short* __restrict__ wTf,// fragment-packed bf16 weights
    const float4* __restrict__ kpq_in,     // [16] precomputed kpq + R2
    const int*   __restrict__ neighbors,   // [N,32] int32
    float*       __restrict__ out)         // [N,128] f32
{
    __shared__ __align__(16) unsigned short wl[MPTS * WSTRIDE];  // 61952 B

    const int tid  = threadIdx.x;
    const int n0   = blockIdx.x * MPTS;
    const int lane = tid & 63;
    const int wv   = tid >> 6;             // wave 0..15 owns points 2wv, 2wv+1
    const int m    = lane & 15;
    const int q    = lane >> 4;

    // ---- stage 1: wave-autonomous; lanes = 64 neighbor slots (2 points) ----
    const int nbv = neighbors[(size_t)n0 * KNB + tid];
    const float px = pos[(size_t)nbv * 3 + 0];
    const float py = pos[(size_t)nbv * 3 + 1];
    const float pz = pos[(size_t)nbv * 3 + 2];

    const int nAu = __builtin_amdgcn_readfirstlane(n0 + wv * 2);  // uniform
    const float cxA = pos[(size_t)nAu * 3 + 0];
    const float cyA = pos[(size_t)nAu * 3 + 1];
    const float czA = pos[(size_t)nAu * 3 + 2];
    const float cxB = pos[(size_t)(nAu + 1) * 3 + 0];
    const float cyB = pos[(size_t)(nAu + 1) * 3 + 1];
    const float czB = pos[(size_t)(nAu + 1) * 3 + 2];

    const bool isA = (lane < 32);
    const float rx = px - (isA ? cxA : cxB);
    const float ry = py - (isA ? cyA : cyB);
    const float rz = pz - (isA ? czA : czB);
    const float d2r = rx * rx + ry * ry + rz * rz;

    // ---- per-lane parallel kp tests: kmask + u16 weights ----
    unsigned int kmask = 0;
    unsigned int wpk[8] = {0u, 0u, 0u, 0u, 0u, 0u, 0u, 0u};
    #pragma unroll
    for (int k = 0; k < KPn; ++k) {
        const float4 kp  = kpq_in[k];
        const float  dot = rx * kp.x + ry * kp.y + rz * kp.z;
        if (dot > 0.5f * (d2r - 0.01f + kp.w)) {        // dist(kp) < 0.1
            const float dd = fmaxf(d2r - 2.f * dot + kp.w, 0.f);
            const float w  = 1.0f - 10.0f * sqrtf(dd);
            const unsigned int w16 = (unsigned int)(w * 65535.0f + 0.5f);
            wpk[k >> 1] |= w16 << (16 * (k & 1));
            kmask |= 1u << k;
        }
    }

    // ---- per-k static accumulate (scalar acc, ballot-driven) -> wl ----
    {
        const int cg = lane >> 3, j8 = lane & 7;
        unsigned short* const wpA = wl + (wv * 2 + 0) * WSTRIDE + cg * 120 + j8;
        unsigned short* const wpB = wl + (wv * 2 + 1) * WSTRIDE + cg * 120 + j8;
        #pragma unroll
        for (int k = 0; k < KPn; ++k) {
            const unsigned long long mk = __ballot((kmask >> k) & 1u);
            float aA = 0.f, aB = 0.f;
            ACC_HALF(mk & 0x00000000ffffffffull, 0, aA);
            ACC_HALF(mk >> 32, 32, aB);
            wpA[k * 8] = (unsigned short)f2bf(aA);
            wpB[k * 8] = (unsigned short)f2bf(aB);
        }
    }
    __syncthreads();   // the ONLY block barrier

    // ---- GEMM2: out[32][128] = wl[32][960] @ W; wave = (mt, nt) tile ----
    {
        const int mt = wv >> 3;            // 0..1  M-tile
        const int nt = wv & 7;             // 0..7  N-tile

        f32x4 o0 = {0.f, 0.f, 0.f, 0.f};
        f32x4 o1 = {0.f, 0.f, 0.f, 0.f};
        const unsigned short* ap = wl + (mt * 16 + m) * WSTRIDE + q * 8;
        const short8* bp = (const short8*)wTf + (size_t)nt * KSTEPS * 64 + lane;

        #pragma unroll 3
        for (int ks = 0; ks < KSTEPS; ks += 2) {
            const short8 a0 = *(const short8*)(ap + ks * 32);
            const short8 b0 = bp[ks * 64];
            o0 = __builtin_amdgcn_mfma_f32_16x16x32_bf16(a0, b0, o0, 0, 0, 0);
            const short8 a1 = *(const short8*)(ap + (ks + 1) * 32);
            const short8 b1 = bp[(ks + 1) * 64];
            o1 = __builtin_amdgcn_mfma_f32_16x16x32_bf16(a1, b1, o1, 0, 0, 0);
        }
        o0 = o0 + o1;

        // C/D layout: col = lane&15, row = q*4 + reg
        const int c = nt * 16 + m;
        #pragma unroll
        for (int r = 0; r < 4; ++r)
            out[(size_t)(n0 + mt * 16 + q * 4 + r) * COUT + c] = o0[r];
    }
}

extern "C" void kernel_launch(void* const* d_in, const int* in_sizes, int n_in,
                              void* d_out, int out_size, void* d_ws, size_t ws_size,
                              hipStream_t stream) {
    const float* pos       = (const float*)d_in[0];
    const float* feats     = (const float*)d_in[1];
    const float* kpts      = (const float*)d_in[2];
    const float* weights   = (const float*)d_in[3];
    const int*   neighbors = (const int*)d_in[4];
    float*       out       = (float*)d_out;
    unsigned short* wTf    = (unsigned short*)d_ws;               // 245760 B
    float4* kpq            = (float4*)((char*)d_ws + WELEMS * 2); // 256 B

    wtrans_kernel<<<(WELEMS + 255) / 256, 256, 0, stream>>>(weights, kpts, wTf, kpq);
    kpconv_kernel<<<NPTS / MPTS, THREADS, 0, stream>>>(
        pos, feats, wTf, kpq, neighbors, out);
}

// Round 10
// 140.441 us; speedup vs baseline: 1.0157x; 1.0157x over previous
//
#include <hip/hip_runtime.h>

#define NPTS  65536
#define KNB   32
#define KPn   15
#define CIN   64
#define COUT  128
#define MPTS  32            // points per block (2 MFMA M-tiles)
#define THREADS 512         // 8 waves/block; 2 blocks/CU = 16 waves/CU
#define WSTRIDE 968         // wl row stride in bf16 elems (960 + 8 pad)
#define NTILE 8             // 128 cols / 16
#define KSTEPS 30           // 960 / 32
#define WELEMS (NTILE * KSTEPS * 64 * 8)    // 122880 bf16 elements

typedef __attribute__((ext_vector_type(8))) short short8;
typedef __attribute__((ext_vector_type(4))) float f32x4;

__device__ __forceinline__ unsigned int f2bf(float f) {
    union { float f; unsigned int i; } v; v.f = f;
    return (v.i + 0x7fffu + ((v.i >> 16) & 1u)) >> 16;   // RNE
}

// ---- prep: pack weights into MFMA B-fragment order (permuted K) + kpq/R2 ----
// K-enum: f = cg*120 + k*8 + j  (cg = c>>3, j = c&7)  ->  orig = k*64 + c
__global__ void wtrans_kernel(const float* __restrict__ w,
                              const float* __restrict__ kpts,
                              unsigned short* __restrict__ wTf,
                              float4* __restrict__ kpq_out) {  // [16]: 15 kpq + {R2}
    const int d = blockIdx.x * 256 + threadIdx.x;
    if (d < WELEMS) {
        const int j    = d & 7;
        const int lane = (d >> 3) & 63;
        const int ks   = (d >> 9) % KSTEPS;
        const int t    = d / (KSTEPS * 512);
        const int f    = ks * 32 + (lane >> 4) * 8 + j;
        const int cg   = f / 120;
        const int rem  = f - cg * 120;
        const int orig = (rem >> 3) * 64 + cg * 8 + (rem & 7);
        const int n    = t * 16 + (lane & 15);
        wTf[d] = (unsigned short)f2bf(w[(size_t)orig * COUT + n]);
    }
    if (blockIdx.x == 0 && threadIdx.x < 16) {
        const int k = threadIdx.x;
        if (k < KPn) {
            const float x = kpts[k * 3 + 0];
            const float y = kpts[k * 3 + 1];
            const float z = kpts[k * 3 + 2];
            kpq_out[k] = make_float4(x, y, z, x * x + y * y + z * z);
        } else {
            float mx = 0.f;
            for (int i = 0; i < KPn; ++i) {
                const float x = kpts[i * 3 + 0];
                const float y = kpts[i * 3 + 1];
                const float z = kpts[i * 3 + 2];
                mx = fmaxf(mx, x * x + y * y + z * z);
            }
            const float R = 0.1f + sqrtf(mx);
            kpq_out[15] = make_float4(R * R, 0.f, 0.f, 0.f);
        }
    }
}

// accumulate one point-half for static k: walk survivor bits, coalesced feats
#define ACC_HALF(MHALF, BASE, ACCV)                                           \
    {                                                                         \
        unsigned long long mh_ = (MHALF);                                     \
        while (mh_) {                                                         \
            const int j_ = (int)__builtin_ctzll(mh_) + (BASE);                \
            mh_ &= mh_ - 1;                                                   \
            const int nb_ = __builtin_amdgcn_readlane(nbv, j_);               \
            const unsigned int wp_ =                                          \
                (unsigned int)__builtin_amdgcn_readlane((int)wpk[k >> 1], j_);\
            const float w_ = (float)((wp_ >> (16 * (k & 1))) & 0xFFFFu) *     \
                             (1.0f / 65535.0f);                               \
            ACCV += w_ * feats[(size_t)nb_ * CIN + lane];                     \
        }                                                                     \
    }

__global__ __launch_bounds__(THREADS, 8) void kpconv_kernel(
    const float* __restrict__ pos,         // [N,3] f32
    const float* __restrict__ feats,       // [N,64] f32
    const unsigned short* __restrict__ wTf,// fragment-packed bf16 weights
    const float4* __restrict__ kpq_in,     // [16] precomputed kpq + R2
    const int*   __restrict__ neighbors,   // [N,32] int32
    float*       __restrict__ out)         // [N,128] f32
{
    __shared__ __align__(16) unsigned short wl[MPTS * WSTRIDE];  // 61952 B

    const int tid  = threadIdx.x;
    const int n0   = blockIdx.x * MPTS;
    const int lane = tid & 63;
    const int wv   = tid >> 6;             // wave 0..7
    const int m    = lane & 15;
    const int q    = lane >> 4;

    // ---- stage 1: wave-autonomous; 2 iterations x 2 points per wave ----
    #pragma unroll
    for (int it = 0; it < 2; ++it) {
        const int pb = n0 + it * 16;       // 16-point group base

        const int nbv = neighbors[(size_t)pb * KNB + tid];
        const float px = pos[(size_t)nbv * 3 + 0];
        const float py = pos[(size_t)nbv * 3 + 1];
        const float pz = pos[(size_t)nbv * 3 + 2];

        const int nAu = __builtin_amdgcn_readfirstlane(pb + wv * 2);  // uniform
        const float cxA = pos[(size_t)nAu * 3 + 0];
        const float cyA = pos[(size_t)nAu * 3 + 1];
        const float czA = pos[(size_t)nAu * 3 + 2];
        const float cxB = pos[(size_t)(nAu + 1) * 3 + 0];
        const float cyB = pos[(size_t)(nAu + 1) * 3 + 1];
        const float czB = pos[(size_t)(nAu + 1) * 3 + 2];

        const bool isA = (lane < 32);
        const float rx = px - (isA ? cxA : cxB);
        const float ry = py - (isA ? cyA : cyB);
        const float rz = pz - (isA ? czA : czB);
        const float d2r = rx * rx + ry * ry + rz * rz;

        // per-lane parallel kp tests: kmask + u16 weights
        unsigned int kmask = 0;
        unsigned int wpk[8] = {0u, 0u, 0u, 0u, 0u, 0u, 0u, 0u};
        #pragma unroll
        for (int k = 0; k < KPn; ++k) {
            const float4 kp  = kpq_in[k];
            const float  dot = rx * kp.x + ry * kp.y + rz * kp.z;
            if (dot > 0.5f * (d2r - 0.01f + kp.w)) {    // dist(kp) < 0.1
                const float dd = fmaxf(d2r - 2.f * dot + kp.w, 0.f);
                const float w  = 1.0f - 10.0f * sqrtf(dd);
                const unsigned int w16 = (unsigned int)(w * 65535.0f + 0.5f);
                wpk[k >> 1] |= w16 << (16 * (k & 1));
                kmask |= 1u << k;
            }
        }

        // per-k static accumulate (scalar acc, ballot-driven) -> wl
        {
            const int cg = lane >> 3, j8 = lane & 7;
            const int rowA = it * 16 + wv * 2;
            unsigned short* const wpA = wl + (rowA + 0) * WSTRIDE + cg * 120 + j8;
            unsigned short* const wpB = wl + (rowA + 1) * WSTRIDE + cg * 120 + j8;
            #pragma unroll
            for (int k = 0; k < KPn; ++k) {
                const unsigned long long mk = __ballot((kmask >> k) & 1u);
                float aA = 0.f, aB = 0.f;
                ACC_HALF(mk & 0x00000000ffffffffull, 0, aA);
                ACC_HALF(mk >> 32, 32, aB);
                wpA[k * 8] = (unsigned short)f2bf(aA);
                wpB[k * 8] = (unsigned short)f2bf(aB);
            }
        }
    }
    __syncthreads();   // the ONLY block barrier

    // ---- GEMM2: out[32][128] = wl[32][960] @ W ----
    // wave = nt; loops mt=0,1 with B-fragments REUSED in registers.
    {
        const int nt = wv;
        f32x4 o00 = {0.f, 0.f, 0.f, 0.f};  // mt=0, even-ks chain
        f32x4 o01 = {0.f, 0.f, 0.f, 0.f};  // mt=0, odd-ks chain
        f32x4 o10 = {0.f, 0.f, 0.f, 0.f};  // mt=1, even-ks chain
        f32x4 o11 = {0.f, 0.f, 0.f, 0.f};  // mt=1, odd-ks chain
        const unsigned short* ap0 = wl + m * WSTRIDE + q * 8;
        const unsigned short* ap1 = wl + (16 + m) * WSTRIDE + q * 8;
        const short8* bp = (const short8*)wTf + (size_t)nt * KSTEPS * 64 + lane;

        #pragma unroll 3
        for (int ks = 0; ks < KSTEPS; ks += 2) {
            const short8 b0  = bp[ks * 64];
            const short8 b1  = bp[(ks + 1) * 64];
            const short8 a00 = *(const short8*)(ap0 + ks * 32);
            const short8 a01 = *(const short8*)(ap0 + (ks + 1) * 32);
            const short8 a10 = *(const short8*)(ap1 + ks * 32);
            const short8 a11 = *(const short8*)(ap1 + (ks + 1) * 32);
            o00 = __builtin_amdgcn_mfma_f32_16x16x32_bf16(a00, b0, o00, 0, 0, 0);
            o10 = __builtin_amdgcn_mfma_f32_16x16x32_bf16(a10, b0, o10, 0, 0, 0);
            o01 = __builtin_amdgcn_mfma_f32_16x16x32_bf16(a01, b1, o01, 0, 0, 0);
            o11 = __builtin_amdgcn_mfma_f32_16x16x32_bf16(a11, b1, o11, 0, 0, 0);
        }
        o00 = o00 + o01;
        o10 = o10 + o11;

        // C/D layout: col = lane&15, row = q*4 + reg
        const int c = nt * 16 + m;
        #pragma unroll
        for (int r = 0; r < 4; ++r)
            out[(size_t)(n0 + q * 4 + r) * COUT + c] = o00[r];
        #pragma unroll
        for (int r = 0; r < 4; ++r)
            out[(size_t)(n0 + 16 + q * 4 + r) * COUT + c] = o10[r];
    }
}

extern "C" void kernel_launch(void* const* d_in, const int* in_sizes, int n_in,
                              void* d_out, int out_size, void* d_ws, size_t ws_size,
                              hipStream_t stream) {
    const float* pos       = (const float*)d_in[0];
    const float* feats     = (const float*)d_in[1];
    const float* kpts      = (const float*)d_in[2];
    const float* weights   = (const float*)d_in[3];
    const int*   neighbors = (const int*)d_in[4];
    float*       out       = (float*)d_out;
    unsigned short* wTf    = (unsigned short*)d_ws;               // 245760 B
    float4* kpq            = (float4*)((char*)d_ws + WELEMS * 2); // 256 B

    wtrans_kernel<<<(WELEMS + 255) / 256, 256, 0, stream>>>(weights, kpts, wTf, kpq);
    kpconv_kernel<<<NPTS / MPTS, THREADS, 0, stream>>>(
        pos, feats, wTf, kpq, neighbors, out);
}

// Round 11
// 133.601 us; speedup vs baseline: 1.0677x; 1.0512x over previous
//
#include <hip/hip_runtime.h>

#define NPTS  65536
#define KNB   32
#define KPn   15
#define CIN   64
#define COUT  128
#define MPTS  16            // points per block (MFMA M of GEMM2)
#define THREADS 512         // 8 waves/block; 4 blocks/CU = 32 waves/CU
#define WSTRIDE 968         // wl row stride in bf16 elems (960 + 8 pad)
#define NTILE 8             // 128 cols / 16
#define KSTEPS 30           // 960 / 32
#define WELEMS (NTILE * KSTEPS * 64 * 8)    // 122880 bf16 elements

typedef __attribute__((ext_vector_type(8))) short short8;
typedef __attribute__((ext_vector_type(4))) float f32x4;

__device__ __forceinline__ unsigned int f2bf(float f) {
    union { float f; unsigned int i; } v; v.f = f;
    return (v.i + 0x7fffu + ((v.i >> 16) & 1u)) >> 16;   // RNE
}

// ---- prep: pack weights into MFMA B-fragment order (permuted K) + kpq/R2 ----
// K-enum: f = cg*120 + k*8 + j  (cg = c>>3, j = c&7)  ->  orig = k*64 + c
__global__ void wtrans_kernel(const float* __restrict__ w,
                              const float* __restrict__ kpts,
                              unsigned short* __restrict__ wTf,
                              float4* __restrict__ kpq_out) {  // [16]: 15 kpq + {R2}
    const int d = blockIdx.x * 256 + threadIdx.x;
    if (d < WELEMS) {
        const int j    = d & 7;
        const int lane = (d >> 3) & 63;
        const int ks   = (d >> 9) % KSTEPS;
        const int t    = d / (KSTEPS * 512);
        const int f    = ks * 32 + (lane >> 4) * 8 + j;
        const int cg   = f / 120;
        const int rem  = f - cg * 120;
        const int orig = (rem >> 3) * 64 + cg * 8 + (rem & 7);
        const int n    = t * 16 + (lane & 15);
        wTf[d] = (unsigned short)f2bf(w[(size_t)orig * COUT + n]);
    }
    if (blockIdx.x == 0 && threadIdx.x < 16) {
        const int k = threadIdx.x;
        if (k < KPn) {
            const float x = kpts[k * 3 + 0];
            const float y = kpts[k * 3 + 1];
            const float z = kpts[k * 3 + 2];
            kpq_out[k] = make_float4(x, y, z, x * x + y * y + z * z);
        } else {
            float mx = 0.f;
            for (int i = 0; i < KPn; ++i) {
                const float x = kpts[i * 3 + 0];
                const float y = kpts[i * 3 + 1];
                const float z = kpts[i * 3 + 2];
                mx = fmaxf(mx, x * x + y * y + z * z);
            }
            const float R = 0.1f + sqrtf(mx);
            kpq_out[15] = make_float4(R * R, 0.f, 0.f, 0.f);
        }
    }
}

// walk one half's match bits: weights via readlane, feats via prefetch slots
#define ACC_HALF(MH, SM, LB, F0, F1, F2, F3, ACCV)                            \
    {                                                                         \
        unsigned int mh_ = (MH);                                              \
        while (mh_) {                                                         \
            const int j_ = __builtin_ctz(mh_);                                \
            mh_ &= mh_ - 1u;                                                  \
            const unsigned int wp_ = (unsigned int)                           \
                __builtin_amdgcn_readlane((int)wpk[k >> 1], j_ + (LB));       \
            const float w_ = (float)((wp_ >> (16 * (k & 1))) & 0xFFFFu) *     \
                             (1.0f / 65535.0f);                               \
            const int i_ = __builtin_popcount((SM) & ((1u << j_) - 1u));      \
            float fv_;                                                        \
            if      (i_ == 0) fv_ = F0;                                       \
            else if (i_ == 1) fv_ = F1;                                       \
            else if (i_ == 2) fv_ = F2;                                       \
            else if (i_ == 3) fv_ = F3;                                       \
            else fv_ = feats[(size_t)                                         \
                __builtin_amdgcn_readlane(nbv, j_ + (LB)) * CIN + lane];      \
            ACCV += w_ * fv_;                                                 \
        }                                                                     \
    }

// prefetch one candidate row (uniform mask walk); no-op if mask exhausted
#define PREFETCH1(T, LB, DST)                                                 \
    if (T) {                                                                  \
        const int j_ = __builtin_ctz(T); (T) &= (T) - 1u;                     \
        DST = feats[(size_t)                                                  \
            __builtin_amdgcn_readlane(nbv, j_ + (LB)) * CIN + lane];          \
    }

__global__ __launch_bounds__(THREADS, 8) void kpconv_kernel(
    const float* __restrict__ pos,         // [N,3] f32
    const float* __restrict__ feats,       // [N,64] f32
    const unsigned short* __restrict__ wTf,// fragment-packed bf16 weights
    const float4* __restrict__ kpq_in,     // [16] precomputed kpq + R2
    const int*   __restrict__ neighbors,   // [N,32] int32
    float*       __restrict__ out)         // [N,128] f32
{
    __shared__ __align__(16) unsigned short wl[MPTS * WSTRIDE];  // 30976 B

    const int tid  = threadIdx.x;
    const int n0   = blockIdx.x * MPTS;
    const int lane = tid & 63;
    const int wv   = tid >> 6;             // wave 0..7 owns points 2wv, 2wv+1
    const int m    = lane & 15;
    const int q    = lane >> 4;

    // ---- stage 1: wave-autonomous; lanes = 64 neighbor slots (2 points) ----
    const int nbv = neighbors[(size_t)n0 * KNB + tid];
    const float px = pos[(size_t)nbv * 3 + 0];
    const float py = pos[(size_t)nbv * 3 + 1];
    const float pz = pos[(size_t)nbv * 3 + 2];

    const int nAu = __builtin_amdgcn_readfirstlane(n0 + wv * 2);  // uniform
    const float cxA = pos[(size_t)nAu * 3 + 0];
    const float cyA = pos[(size_t)nAu * 3 + 1];
    const float czA = pos[(size_t)nAu * 3 + 2];
    const float cxB = pos[(size_t)(nAu + 1) * 3 + 0];
    const float cyB = pos[(size_t)(nAu + 1) * 3 + 1];
    const float czB = pos[(size_t)(nAu + 1) * 3 + 2];
    const float R2  = kpq_in[15].x;                               // uniform

    const bool isA = (lane < 32);
    const float rx = px - (isA ? cxA : cxB);
    const float ry = py - (isA ? cyA : cyB);
    const float rz = pz - (isA ? czA : czB);
    const float d2r = rx * rx + ry * ry + rz * rz;

    // ---- early radius ballot (superset of kp matches) + feats PREFETCH ----
    // dist(kp)<0.1 => |r| < 0.1+max|kp| = R, so candidates cover all matches.
    const unsigned long long cand = __ballot(d2r < R2);           // ~6% set
    const unsigned int smA = (unsigned int)(cand & 0xffffffffull);
    const unsigned int smB = (unsigned int)(cand >> 32);

    float fA0 = 0.f, fA1 = 0.f, fA2 = 0.f, fA3 = 0.f;
    float fB0 = 0.f, fB1 = 0.f, fB2 = 0.f, fB3 = 0.f;
    {
        unsigned int t = smA;
        PREFETCH1(t, 0, fA0); PREFETCH1(t, 0, fA1);
        PREFETCH1(t, 0, fA2); PREFETCH1(t, 0, fA3);
        unsigned int u = smB;
        PREFETCH1(u, 32, fB0); PREFETCH1(u, 32, fB1);
        PREFETCH1(u, 32, fB2); PREFETCH1(u, 32, fB3);
    }

    // ---- per-lane parallel kp tests (hides prefetch latency) ----
    unsigned int kmask = 0;
    unsigned int wpk[8] = {0u, 0u, 0u, 0u, 0u, 0u, 0u, 0u};
    #pragma unroll
    for (int k = 0; k < KPn; ++k) {
        const float4 kp  = kpq_in[k];
        const float  dot = rx * kp.x + ry * kp.y + rz * kp.z;
        if (dot > 0.5f * (d2r - 0.01f + kp.w)) {        // dist(kp) < 0.1
            const float dd = fmaxf(d2r - 2.f * dot + kp.w, 0.f);
            const float w  = 1.0f - 10.0f * sqrtf(dd);
            const unsigned int w16 = (unsigned int)(w * 65535.0f + 0.5f);
            wpk[k >> 1] |= w16 << (16 * (k & 1));
            kmask |= 1u << k;
        }
    }

    // ---- per-k static accumulate: no vmem in the hot loop ----
    {
        const int cg = lane >> 3, j8 = lane & 7;
        unsigned short* const wpA = wl + (wv * 2 + 0) * WSTRIDE + cg * 120 + j8;
        unsigned short* const wpB = wl + (wv * 2 + 1) * WSTRIDE + cg * 120 + j8;
        #pragma unroll
        for (int k = 0; k < KPn; ++k) {
            const unsigned long long mk = __ballot((kmask >> k) & 1u);
            float aA = 0.f, aB = 0.f;
            ACC_HALF((unsigned int)(mk & 0xffffffffull), smA, 0,
                     fA0, fA1, fA2, fA3, aA);
            ACC_HALF((unsigned int)(mk >> 32), smB, 32,
                     fB0, fB1, fB2, fB3, aB);
            wpA[k * 8] = (unsigned short)f2bf(aA);
            wpB[k * 8] = (unsigned short)f2bf(aB);
        }
    }
    __syncthreads();   // the ONLY block barrier

    // ---- GEMM2: out[16][128] = wl[16][960] @ W; one N-tile per wave ----
    {
        f32x4 o0 = {0.f, 0.f, 0.f, 0.f};
        f32x4 o1 = {0.f, 0.f, 0.f, 0.f};
        const unsigned short* ap = wl + m * WSTRIDE + q * 8;
        const short8* bp = (const short8*)wTf + (size_t)wv * KSTEPS * 64 + lane;

        #pragma unroll 3
        for (int ks = 0; ks < KSTEPS; ks += 2) {
            const short8 a0 = *(const short8*)(ap + ks * 32);
            const short8 b0 = bp[ks * 64];
            o0 = __builtin_amdgcn_mfma_f32_16x16x32_bf16(a0, b0, o0, 0, 0, 0);
            const short8 a1 = *(const short8*)(ap + (ks + 1) * 32);
            const short8 b1 = bp[(ks + 1) * 64];
            o1 = __builtin_amdgcn_mfma_f32_16x16x32_bf16(a1, b1, o1, 0, 0, 0);
        }
        o0 = o0 + o1;

        // C/D layout: col = lane&15, row = q*4 + reg
        const int c = wv * 16 + m;
        #pragma unroll
        for (int r = 0; r < 4; ++r)
            out[(size_t)(n0 + q * 4 + r) * COUT + c] = o0[r];
    }
}

extern "C" void kernel_launch(void* const* d_in, const int* in_sizes, int n_in,
                              void* d_out, int out_size, void* d_ws, size_t ws_size,
                              hipStream_t stream) {
    const float* pos       = (const float*)d_in[0];
    const float* feats     = (const float*)d_in[1];
    const float* kpts      = (const float*)d_in[2];
    const float* weights   = (const float*)d_in[3];
    const int*   neighbors = (const int*)d_in[4];
    float*       out       = (float*)d_out;
    unsigned short* wTf    = (unsigned short*)d_ws;               // 245760 B
    float4* kpq            = (float4*)((char*)d_ws + WELEMS * 2); // 256 B

    wtrans_kernel<<<(WELEMS + 255) / 256, 256, 0, stream>>>(weights, kpts, wTf, kpq);
    kpconv_kernel<<<NPTS / MPTS, THREADS, 0, stream>>>(
        pos, feats, wTf, kpq, neighbors, out);
}